// Round 1
// 394.961 us; speedup vs baseline: 1.1707x; 1.1707x over previous
//
#include <hip/hip_runtime.h>

typedef _Float16 f16;
typedef _Float16 f16x4 __attribute__((ext_vector_type(4)));
typedef _Float16 f16x8 __attribute__((ext_vector_type(8)));
typedef float f32x4 __attribute__((ext_vector_type(4)));

#define EMB 1024
#define SEQL 4096
#define BATCH 4
#define NH 16
#define HD 64
#define BH 64           // BATCH*NH
#define MROWS 16384     // BATCH*SEQL
#define KVSPLIT 16      // l-chunks for split-K kv

#define GLOAD_LDS(gp, lp) \
    __builtin_amdgcn_global_load_lds((const __attribute__((address_space(1))) void*)(gp), \
                                     (__attribute__((address_space(3))) void*)(lp), 16, 0, 0)

// ---------------- fp32 -> fp16 convert ----------------
__global__ void cvt_kernel(const float* __restrict__ in, f16* __restrict__ out, int n4) {
    int i = blockIdx.x * blockDim.x + threadIdx.x;
    if (i < n4) {
        float4 v = ((const float4*)in)[i];
        f16x4 o = { (f16)v.x, (f16)v.y, (f16)v.z, (f16)v.w };
        ((f16x4*)out)[i] = o;
    }
}

struct WPtrs { const float* p[5]; };

__global__ void cvt_w_kernel(WPtrs wp, f16* __restrict__ out) {
    int i = blockIdx.x * blockDim.x + threadIdx.x;
    int wsel = blockIdx.y;
    const float4* src = (const float4*)wp.p[wsel];
    float4 v = src[i];
    f16x4 o = { (f16)v.x, (f16)v.y, (f16)v.z, (f16)v.w };
    ((f16x4*)(out + (size_t)wsel * EMB * EMB))[i] = o;
}

__global__ void zero_kernel(float4* __restrict__ p, int n4) {
    int i = blockIdx.x * blockDim.x + threadIdx.x;
    if (i < n4) p[i] = float4{0.f, 0.f, 0.f, 0.f};
}

// ---------------- 256x256 8-phase counted-vmcnt MFMA GEMM ----------------
// C[m][n] = act( sum_k A[m][k]*Bt[n][k] ), A: MxK row-major, Bt: NxK row-major.
// 512 threads = 8 waves (2M x 4N). LDS: per-operand 2 x [256][64] f16 (128 KiB).
// Staging granularity = half-tile (128 rows x 64 cols) = 2 x global_load_lds(16B)/thread.
// XOR slot swizzle: logical k-chunk c of row r lives at physical chunk c^(r&7)
// (pre-swizzled on the global source address; ds_read applies the same XOR).
// Phase schedule per K-tile kt (C-quadrants are of the BLOCK tile; all 8 waves
// cooperate on one 128x128 quadrant per phase):
//   ph1 Q(0,0): read A-h0,B-h0 frags; stage B-h0(kt+1); vmcnt(6); bar; 16 MFMA; bar
//   ph2 Q(0,1): read B-h1 (reuse A); stage B-h1(kt+1); vmcnt(6); ...
//   ph3 Q(1,1): read A-h1 (reuse B); stage A-h1(kt+1); vmcnt(6); ...
//   ph4 Q(1,0): read B-h0 (reuse A); stage A-h0(kt+2); vmcnt(6); ...
// Every half is issued exactly 4 phases before first consumption; vmcnt(6) leaves the
// 3 newest half-tiles in flight => never drains. Tail waits tighten 6 -> 4 -> 2 -> 0.
// MODE 0: fp32 out, row-major            [final Wo GEMM]
// MODE 3: f16 out, merged q|u            (col<1024 -> relu/8 q ; else silu u)
// MODE 4: f16 out, merged kT|vT          (row<1024 -> relu/8 kT ; else vT)

#define FENCE asm volatile("" ::: "memory")
#define WAITV(N) asm volatile("s_waitcnt vmcnt(" #N ")" ::: "memory")
#define BAR do { FENCE; __builtin_amdgcn_s_barrier(); FENCE; } while (0)

template<int MODE>
__global__ __launch_bounds__(512, 2) void gemm_kernel(
    const f16* __restrict__ A, const f16* __restrict__ Bt,
    void* __restrict__ Cv, int M, int N, int K)
{
    __shared__ f16 As[2][256 * 64];
    __shared__ f16 Bs[2][256 * 64];

    const int tid  = threadIdx.x;
    const int lane = tid & 63;
    const int w    = tid >> 6;      // wave 0..7
    const int rw   = lane & 15;
    const int quad = lane >> 4;
    const int wm   = w >> 2;        // 0..1  (64-row slice within quadrant)
    const int wn   = w & 3;         // 0..3  (32-col slice within quadrant)
    const int m0 = blockIdx.y * 256;
    const int n0 = blockIdx.x * 256;
    const size_t Ks = (size_t)K;
    const int NT = K >> 6;

    // ---- staging addresses: thread covers row (w*8 + lane>>3) (+64 for 2nd load),
    //      physical chunk lane&7 holds logical chunk (lane&7)^(lane>>3)
    const int srow8 = lane >> 3;
    const int slog  = (lane & 7) ^ srow8;
    const f16* gA = A  + (size_t)(m0 + w * 8 + srow8) * Ks + slog * 8;
    const f16* gB = Bt + (size_t)(n0 + w * 8 + srow8) * Ks + slog * 8;
    const int lst = w * 512;        // f16 units; +4096 for 2nd load

#define STAGE_A(H, T, BUF) do { \
    GLOAD_LDS(gA + (size_t)((H) * 128 +  0) * Ks + (T) * 64, &As[BUF][(H) * 8192 + lst]); \
    GLOAD_LDS(gA + (size_t)((H) * 128 + 64) * Ks + (T) * 64, &As[BUF][(H) * 8192 + 4096 + lst]); \
} while (0)
#define STAGE_B(H, T, BUF) do { \
    GLOAD_LDS(gB + (size_t)((H) * 128 +  0) * Ks + (T) * 64, &Bs[BUF][(H) * 8192 + lst]); \
    GLOAD_LDS(gB + (size_t)((H) * 128 + 64) * Ks + (T) * 64, &Bs[BUF][(H) * 8192 + 4096 + lst]); \
} while (0)

    // ---- fragment read bases: row r, k-slice s -> slot ((s*4+quad)^(rw&7))*8
    const int rw7   = rw & 7;
    const int s0o   = ( quad      ^ rw7) * 8;
    const int s1o   = ((quad + 4) ^ rw7) * 8;
    const int abase = (wm * 64 + rw) * 64;
    const int bbase = (wn * 32 + rw) * 64;

    f32x4 acc[2][2][4][2] = {};
    f16x8 af[4][2], bf[2][2];

#define READ_A(QM, BUF) do { \
    _Pragma("unroll") \
    for (int mi = 0; mi < 4; ++mi) { \
        af[mi][0] = *(const f16x8*)&As[BUF][(QM) * 8192 + abase + mi * 1024 + s0o]; \
        af[mi][1] = *(const f16x8*)&As[BUF][(QM) * 8192 + abase + mi * 1024 + s1o]; \
    } \
} while (0)
#define READ_B(QN, BUF) do { \
    _Pragma("unroll") \
    for (int nj = 0; nj < 2; ++nj) { \
        bf[nj][0] = *(const f16x8*)&Bs[BUF][(QN) * 8192 + bbase + nj * 1024 + s0o]; \
        bf[nj][1] = *(const f16x8*)&Bs[BUF][(QN) * 8192 + bbase + nj * 1024 + s1o]; \
    } \
} while (0)
#define MFMA_Q(QM, QN) do { \
    __builtin_amdgcn_s_setprio(1); \
    _Pragma("unroll") \
    for (int mi = 0; mi < 4; ++mi) \
        _Pragma("unroll") \
        for (int nj = 0; nj < 2; ++nj) { \
            acc[QM][QN][mi][nj] = __builtin_amdgcn_mfma_f32_16x16x32_f16(bf[nj][0], af[mi][0], acc[QM][QN][mi][nj], 0, 0, 0); \
            acc[QM][QN][mi][nj] = __builtin_amdgcn_mfma_f32_16x16x32_f16(bf[nj][1], af[mi][1], acc[QM][QN][mi][nj], 0, 0, 0); \
        } \
    __builtin_amdgcn_s_setprio(0); \
} while (0)

    // ---- prologue: tile 0 fully + A-h0(1); wait leaves A-h0(1) in flight
    STAGE_A(0, 0, 0);
    STAGE_B(0, 0, 0);
    STAGE_B(1, 0, 0);
    STAGE_A(1, 0, 0);
    if (NT > 1) { STAGE_A(0, 1, 1); WAITV(2); } else { WAITV(0); }
    BAR;

    for (int kt = 0; kt < NT; ++kt) {
        const int cur = kt & 1, nxt = cur ^ 1;
        const bool p1 = (kt + 1 < NT), p2 = (kt + 2 < NT);
        // phase 1: Q(0,0)
        READ_A(0, cur); READ_B(0, cur);
        if (p1) { STAGE_B(0, kt + 1, nxt); WAITV(6); } else { WAITV(2); }
        BAR; MFMA_Q(0, 0); BAR;
        // phase 2: Q(0,1)
        READ_B(1, cur);
        if (p1) { STAGE_B(1, kt + 1, nxt); WAITV(6); } else { WAITV(0); }
        BAR; MFMA_Q(0, 1); BAR;
        // phase 3: Q(1,1)
        READ_A(1, cur);
        if (p1) { STAGE_A(1, kt + 1, nxt); WAITV(6); } else { WAITV(0); }
        BAR; MFMA_Q(1, 1); BAR;
        // phase 4: Q(1,0)  (A-h0 of kt+2 goes into the CURRENT buffer: h0 reads done at ph2)
        READ_B(0, cur);
        if (p2) { STAGE_A(0, kt + 2, cur); WAITV(6); } else { WAITV(4); }
        BAR; MFMA_Q(1, 0); BAR;
    }

    // ---- epilogue: swapped-operand layout: m = ...+rw ; regs r -> n = ...+quad*4+r
    #pragma unroll
    for (int qm = 0; qm < 2; ++qm)
    #pragma unroll
    for (int qn = 0; qn < 2; ++qn)
    #pragma unroll
    for (int mi = 0; mi < 4; ++mi)
    #pragma unroll
    for (int nj = 0; nj < 2; ++nj) {
        const int m_idx = m0 + qm * 128 + wm * 64 + mi * 16 + rw;
        const int n_idx = n0 + qn * 128 + wn * 32 + nj * 16 + quad * 4;
        f32x4 a = acc[qm][qn][mi][nj];
        if (MODE == 0) {
            float4 vv = { a[0], a[1], a[2], a[3] };
            *(float4*)&((float*)Cv)[(size_t)m_idx * N + n_idx] = vv;
        } else if (MODE == 3) {
            int sel = n_idx >> 10, e = n_idx & 1023;
            int b = m_idx >> 12, l = m_idx & 4095, h = e >> 6, hdi = e & 63;
            f16x4 o;
            #pragma unroll
            for (int r = 0; r < 4; r++) {
                float v = a[r];
                o[r] = (f16)(sel ? (v / (1.0f + __expf(-v))) : (fmaxf(v, 0.0f) * 0.125f));
            }
            *(f16x4*)&((f16*)Cv)[(size_t)sel * MROWS * EMB +
                                 (((size_t)(b * 16 + h) * 4096 + l) << 6) + hdi] = o;
        } else {
            int sel = m_idx >> 10, e = m_idx & 1023;
            int b = n_idx >> 12, l = n_idx & 4095;
            f16x4 o;
            #pragma unroll
            for (int r = 0; r < 4; r++) {
                float v = a[r];
                o[r] = (f16)(sel ? v : (fmaxf(v, 0.0f) * 0.125f));
            }
            *(f16x4*)&((f16*)Cv)[(size_t)sel * MROWS * EMB +
                                 (((size_t)b * 1024 + e) << 12) + l] = o;
        }
    }
#undef STAGE_A
#undef STAGE_B
#undef READ_A
#undef READ_B
#undef MFMA_Q
}

// ---------------- split-K kv: kv[m][n] += sum_{l in chunk} k[l][m]*v[l][n] ----------------
__global__ __launch_bounds__(256) void kv_split_kernel(
    const f16* __restrict__ kT, const f16* __restrict__ vT, float* __restrict__ kv32)
{
    const int bh    = blockIdx.x;
    const int chunk = blockIdx.y;
    const int lane  = threadIdx.x & 63;
    const int w     = threadIdx.x >> 6;
    const int rw    = lane & 15;
    const int quad  = lane >> 4;
    const int lbase = chunk * (SEQL / KVSPLIT);

    const f16* kp = kT + (size_t)bh * HD * SEQL + (size_t)(w * 16 + rw) * SEQL + lbase + quad * 8;
    const f16* vp = vT + (size_t)bh * HD * SEQL + (size_t)rw * SEQL + lbase + quad * 8;

    f32x4 acc[4] = {};
    for (int k0 = 0; k0 < SEQL / KVSPLIT; k0 += 32) {
        f16x8 a = *(const f16x8*)(kp + k0);
        #pragma unroll
        for (int t = 0; t < 4; t++) {
            f16x8 b = *(const f16x8*)(vp + (size_t)16 * t * SEQL + k0);
            acc[t] = __builtin_amdgcn_mfma_f32_16x16x32_f16(a, b, acc[t], 0, 0, 0);
        }
    }
    float* out = kv32 + (size_t)bh * HD * HD;
    #pragma unroll
    for (int t = 0; t < 4; t++)
        #pragma unroll
        for (int r = 0; r < 4; r++)
            atomicAdd(&out[(w * 16 + quad * 4 + r) * 64 + t * 16 + rw], acc[t][r]);
}

// ---------------- out = SRMSNorm(q @ kv) * u, written to (b,l,emb) f16 ----------------
__global__ __launch_bounds__(256) void ret_out_kernel(
    const f16* __restrict__ q, const f16* __restrict__ u,
    const float* __restrict__ kv32, f16* __restrict__ o)
{
    const int bh    = blockIdx.x;
    const int chunk = blockIdx.y;
    const int lane  = threadIdx.x & 63;
    const int w     = threadIdx.x >> 6;
    const int rw    = lane & 15;
    const int quad  = lane >> 4;

    const float* kvp = kv32 + (size_t)bh * 4096;
    f16x8 bf[2][4];
    #pragma unroll
    for (int s = 0; s < 2; s++)
        #pragma unroll
        for (int t = 0; t < 4; t++)
            #pragma unroll
            for (int j = 0; j < 8; j++)
                bf[s][t][j] = (f16)kvp[(s * 32 + quad * 8 + j) * 64 + t * 16 + rw];

    const f16* qp = q + (size_t)bh * SEQL * HD;
    const f16* up = u + (size_t)bh * SEQL * HD;
    const int b = bh >> 4, h = bh & 15;
    f16* op = o + (size_t)b * SEQL * EMB + h * 64;

    const int l_wave = chunk * 512 + w * 128;
    for (int s = 0; s < 8; s++) {
        const int l0 = l_wave + s * 16;
        f16x8 a0 = *(const f16x8*)(qp + (size_t)(l0 + rw) * 64 + quad * 8);
        f16x8 a1 = *(const f16x8*)(qp + (size_t)(l0 + rw) * 64 + 32 + quad * 8);
        f32x4 acc[4] = {};
        #pragma unroll
        for (int t = 0; t < 4; t++) {
            acc[t] = __builtin_amdgcn_mfma_f32_16x16x32_f16(a0, bf[0][t], acc[t], 0, 0, 0);
            acc[t] = __builtin_amdgcn_mfma_f32_16x16x32_f16(a1, bf[1][t], acc[t], 0, 0, 0);
        }
        float inv[4];
        #pragma unroll
        for (int r = 0; r < 4; r++) {
            float ss = acc[0][r] * acc[0][r] + acc[1][r] * acc[1][r]
                     + acc[2][r] * acc[2][r] + acc[3][r] * acc[3][r];
            #pragma unroll
            for (int msk = 1; msk < 16; msk <<= 1)
                ss += __shfl_xor(ss, msk, 16);
            inv[r] = 8.0f / fmaxf(sqrtf(ss), 8e-12f);
        }
        #pragma unroll
        for (int t = 0; t < 4; t++)
            #pragma unroll
            for (int r = 0; r < 4; r++) {
                int l = l0 + quad * 4 + r;
                int col = t * 16 + rw;
                float uval = (float)up[(size_t)l * 64 + col];
                op[(size_t)l * EMB + col] = (f16)(acc[t][r] * inv[r] * uval);
            }
    }
}

extern "C" void kernel_launch(void* const* d_in, const int* in_sizes, int n_in,
                              void* d_out, int out_size, void* d_ws, size_t ws_size,
                              hipStream_t stream)
{
    const float* x = (const float*)d_in[0];
    // dst slot order: Wq, Wu, Wk, Wv, Wo  (so [Wq;Wu] and [Wk;Wv] are contiguous)
    WPtrs wp;
    wp.p[0] = (const float*)d_in[1];  // Wq
    wp.p[1] = (const float*)d_in[4];  // Wu
    wp.p[2] = (const float*)d_in[2];  // Wk
    wp.p[3] = (const float*)d_in[3];  // Wv
    wp.p[4] = (const float*)d_in[5];  // Wo

    char* ws = (char*)d_ws;
    size_t off = 0;
    f16* x16 = (f16*)(ws + off); off += (size_t)MROWS * EMB * 2;
    f16* w16 = (f16*)(ws + off); off += (size_t)5 * EMB * EMB * 2;
    f16* qb  = (f16*)(ws + off); off += (size_t)MROWS * EMB * 2;   // q
    f16* ub  = (f16*)(ws + off); off += (size_t)MROWS * EMB * 2;   // u (contiguous after q)
    f16* kTb = (f16*)(ws + off); off += (size_t)MROWS * EMB * 2;   // kT
    f16* vTb = (f16*)(ws + off); off += (size_t)MROWS * EMB * 2;   // vT (contiguous after kT)
    float* kv32 = (float*)(ws + off); off += (size_t)BH * HD * HD * 4;
    f16* ob  = x16;  // reuse: x16 dead after the two merged projection GEMMs
    (void)ub; (void)vTb;

    cvt_kernel<<<(MROWS * EMB / 4) / 256, 256, 0, stream>>>(x, x16, MROWS * EMB / 4);
    cvt_w_kernel<<<dim3((EMB * EMB / 4) / 256, 5), 256, 0, stream>>>(wp, w16);
    zero_kernel<<<(BH * HD * HD / 4 + 255) / 256, 256, 0, stream>>>((float4*)kv32, BH * HD * HD / 4);

    f16* Wqu = w16;                              // [Wq; Wu]  2048 x 1024
    f16* Wkv = w16 + (size_t)2 * EMB * EMB;      // [Wk; Wv]  2048 x 1024
    f16* Wo  = w16 + (size_t)4 * EMB * EMB;

    dim3 blk(512);
    // q|u = acts(x [Wq;Wu]^T) -> (b,h,l,hd) pair
    gemm_kernel<3><<<dim3(8, 64), blk, 0, stream>>>(x16, Wqu, qb, MROWS, 2 * EMB, EMB);
    // kT|vT = acts([Wk;Wv] x^T) -> (b,h,hd,l) pair
    gemm_kernel<4><<<dim3(64, 8), blk, 0, stream>>>(Wkv, x16, kTb, 2 * EMB, MROWS, EMB);

    // retention core
    kv_split_kernel<<<dim3(BH, KVSPLIT), dim3(256), 0, stream>>>(kTb, vTb, kv32);
    ret_out_kernel<<<dim3(BH, 8), dim3(256), 0, stream>>>(qb, ub, kv32, ob);

    // final: out = o @ Wo^T, fp32
    gemm_kernel<0><<<dim3(4, 64), blk, 0, stream>>>(ob, Wo, d_out, MROWS, EMB, EMB);
}